// Round 5
// baseline (111.412 us; speedup 1.0000x reference)
//
#include <hip/hip_runtime.h>
#include <hip/hip_bf16.h>
#include <math.h>

typedef short short8  __attribute__((ext_vector_type(8)));
typedef float floatx4 __attribute__((ext_vector_type(4)));
typedef char  charx8  __attribute__((ext_vector_type(8)));
typedef int   intx4   __attribute__((ext_vector_type(4)));
typedef int   intx16  __attribute__((ext_vector_type(16)));

#define NX 8192
#define NY 8192
#define KD 512
#define QS 26.0f                   // i8 quant scale
#define INV_QS2 (1.0f / (26.0f * 26.0f))
#define TILEB (256 * 128)          // one K-tile (BK=128 i8) = 32 KB

// ---- order-preserving float<->uint transform for atomicMax on floats ----
__device__ inline unsigned int f2u_ord(float x) {
    unsigned int u = __float_as_uint(x);
    return (u & 0x80000000u) ? ~u : (u | 0x80000000u);
}
__device__ inline float u2f_ord(unsigned int u) {
    return (u & 0x80000000u) ? __uint_as_float(u & 0x7fffffffu)
                             : __uint_as_float(~u);
}

__device__ inline char q8(float x) {
    float xs = fmaxf(-127.0f, fminf(127.0f, x * QS));
    return (char)(int)rintf(xs);
}
__device__ inline charx8 qpack8(const float4 u, const float4 v) {
    charx8 r;
    r[0] = q8(u.x); r[1] = q8(u.y); r[2] = q8(u.z); r[3] = q8(u.w);
    r[4] = q8(v.x); r[5] = q8(v.y); r[6] = q8(v.z); r[7] = q8(v.w);
    return r;
}

__device__ __forceinline__ void gload_lds16(const void* g, void* l) {
    __builtin_amdgcn_global_load_lds(
        (const __attribute__((address_space(1))) unsigned int*)g,
        (__attribute__((address_space(3))) unsigned int*)l, 16, 0, 0);
}

// ================= kernel 0: f32 -> i8 quantize + inv-norms + rowmax init ===
// One wave per row (512 f32 = 64 lanes x 8).
__global__ __launch_bounds__(256) void convert_kernel(
    const float* __restrict__ ex, const float* __restrict__ ey,
    char* __restrict__ exq, char* __restrict__ eyq,
    float* __restrict__ inv_nx, float* __restrict__ inv_ny,
    unsigned int* __restrict__ rowmax_u) {
    const int tid  = threadIdx.x;
    const int wid  = tid >> 6, lane = tid & 63;
    const int gr   = blockIdx.x * 4 + wid;          // 0..16383

    const bool isx = (gr < NX);
    const int row  = isx ? gr : gr - NX;
    const float* src = isx ? ex : ey;
    char* dst        = isx ? exq : eyq;
    float* inv       = isx ? inv_nx : inv_ny;

    const float4* p = reinterpret_cast<const float4*>(src + (size_t)row * KD) + lane * 2;
    float4 v0 = p[0], v1 = p[1];
    *reinterpret_cast<charx8*>(dst + (size_t)row * KD + lane * 8) = qpack8(v0, v1);

    float s = v0.x*v0.x + v0.y*v0.y + v0.z*v0.z + v0.w*v0.w
            + v1.x*v1.x + v1.y*v1.y + v1.z*v1.z + v1.w*v1.w;
    #pragma unroll
    for (int off = 32; off; off >>= 1) s += __shfl_xor(s, off);
    if (lane == 0) {
        inv[row] = 1.0f / sqrtf(s);
        if (isx) rowmax_u[row] = 0u;    // below transform of any real float
    }
}

// ================= kernel 1: 256x256 i8 MFMA GEMM (BK=128, 4 phases) ========
// 8 waves (2M x 4N), per-wave 128x64 output = 4x2 tiles of 32x32.
// Double-buffered 128 KiB LDS; global_load_lds staging with counted vmcnt;
// XOR chunk swizzle via pre-swizzled global source (rule #21); setprio (T5).
__global__ __launch_bounds__(512, 2) void gemm8p_i8_kernel(
    const char* __restrict__ exq, const char* __restrict__ eyq,
    const float* __restrict__ inv_ny, unsigned int* __restrict__ rowmax_u) {
    __shared__ char As[2][TILEB];   // [buf][row*128 + kbyte], row stride 128 B
    __shared__ char Bs[2][TILEB];

    const int tid   = threadIdx.x;
    const int lane  = tid & 63;
    const int wid   = tid >> 6;     // 0..7
    const int wr    = wid >> 2;     // 0..1 (M)
    const int wc    = wid & 3;      // 0..3 (N)
    const int hi    = lane >> 5;    // 0..1 (k-half within fragment)
    const int cl    = lane & 31;    // row/col within 32-tile
    const int m0    = blockIdx.x * 256;
    const int n0    = blockIdx.y * 256;

    // staging map: 512 threads x 16B = 64 rows (of 128 B) per issue
    const int sr  = tid >> 3;       // 0..63 row within quarter
    const int sc  = tid & 7;        // chunk 0..7
    const int scs = sc ^ (sr & 7);  // pre-swizzled global source chunk

    intx16 acc[4][2];
    #pragma unroll
    for (int i = 0; i < 4; i++)
        #pragma unroll
        for (int j = 0; j < 2; j++)
            #pragma unroll
            for (int e = 0; e < 16; e++) acc[i][j][e] = 0;

    intx4 af[2][4];   // current m-half: 2 M-tiles x 4 k-steps
    intx4 bf[2][4];   // both N-tiles x 4 k-steps (persist per K-tile)

    auto stageA = [&](int st, int R0) {
        const char* src = exq + (size_t)(m0 + R0 + sr) * KD + (st << 7) + (scs << 4);
        gload_lds16(src, &As[st & 1][R0 * 128 + tid * 16]);
    };
    auto stageB = [&](int st, int R0) {
        const char* src = eyq + (size_t)(n0 + R0 + sr) * KD + (st << 7) + (scs << 4);
        gload_lds16(src, &Bs[st & 1][R0 * 128 + tid * 16]);
    };
    // fragment read: row, k-step ks (K=32 each): chunk = ks*2 + hi
    auto rdA = [&](int cur, int row, int ks) -> intx4 {
        return *reinterpret_cast<const intx4*>(
            &As[cur][row * 128 + (((ks * 2 + hi) ^ (row & 7)) << 4)]);
    };
    auto rdB = [&](int cur, int row, int ks) -> intx4 {
        return *reinterpret_cast<const intx4*>(
            &Bs[cur][row * 128 + (((ks * 2 + hi) ^ (row & 7)) << 4)]);
    };

    // prologue: stage tile 0 (order: B0,B64,B128,B192,A0,A128,A64,A192)
    stageB(0, 0);  stageB(0, 64); stageB(0, 128); stageB(0, 192);
    stageA(0, 0);  stageA(0, 128);                 // needed at phase 0
    stageA(0, 64); stageA(0, 192);                 // needed at phase 2

    for (int t = 0; t < 4; ++t) {                  // KD/128 = 4 K-tiles
        const int cur = t & 1;
        const int st  = (t + 1) & 3;   // wraps at t=3: wasted re-stage of
                                       // tile 0 keeps vmcnt counts uniform
        // ---- K-tile boundary: all but the 2 newest (A64,A192) done ----
        asm volatile("s_waitcnt vmcnt(2)" ::: "memory");
        __builtin_amdgcn_s_barrier();

        // ======== phase 0: (mh=0, nh=0) ========
        #pragma unroll
        for (int mi = 0; mi < 2; mi++) {
            int arow = wr * 128 + mi * 32 + cl;
            #pragma unroll
            for (int ks = 0; ks < 4; ks++) af[mi][ks] = rdA(cur, arow, ks);
        }
        {
            int brow = wc * 64 + cl;               // nh=0
            #pragma unroll
            for (int ks = 0; ks < 4; ks++) bf[0][ks] = rdB(cur, brow, ks);
        }
        stageB(st, 0); stageB(st, 64);
        __builtin_amdgcn_s_barrier();
        __builtin_amdgcn_s_setprio(1);
        #pragma unroll
        for (int mi = 0; mi < 2; mi++)
            #pragma unroll
            for (int ks = 0; ks < 4; ks++)
                acc[mi][0] = __builtin_amdgcn_mfma_i32_32x32x32_i8(
                    af[mi][ks], bf[0][ks], acc[mi][0], 0, 0, 0);
        __builtin_amdgcn_s_setprio(0);
        __builtin_amdgcn_s_barrier();

        // ======== phase 1: (mh=0, nh=1) ========
        {
            int brow = wc * 64 + 32 + cl;          // nh=1
            #pragma unroll
            for (int ks = 0; ks < 4; ks++) bf[1][ks] = rdB(cur, brow, ks);
        }
        stageB(st, 128); stageB(st, 192);
        asm volatile("s_waitcnt vmcnt(4)" ::: "memory");  // drain A64,A192 of cur
        __builtin_amdgcn_s_barrier();
        __builtin_amdgcn_s_setprio(1);
        #pragma unroll
        for (int mi = 0; mi < 2; mi++)
            #pragma unroll
            for (int ks = 0; ks < 4; ks++)
                acc[mi][1] = __builtin_amdgcn_mfma_i32_32x32x32_i8(
                    af[mi][ks], bf[1][ks], acc[mi][1], 0, 0, 0);
        __builtin_amdgcn_s_setprio(0);
        __builtin_amdgcn_s_barrier();

        // ======== phase 2: (mh=1, nh=1) ========
        #pragma unroll
        for (int mi = 0; mi < 2; mi++) {
            int arow = wr * 128 + 64 + mi * 32 + cl;
            #pragma unroll
            for (int ks = 0; ks < 4; ks++) af[mi][ks] = rdA(cur, arow, ks);
        }
        stageA(st, 0); stageA(st, 128);
        __builtin_amdgcn_s_barrier();
        __builtin_amdgcn_s_setprio(1);
        #pragma unroll
        for (int mi = 0; mi < 2; mi++)
            #pragma unroll
            for (int ks = 0; ks < 4; ks++)
                acc[2 + mi][1] = __builtin_amdgcn_mfma_i32_32x32x32_i8(
                    af[mi][ks], bf[1][ks], acc[2 + mi][1], 0, 0, 0);
        __builtin_amdgcn_s_setprio(0);
        __builtin_amdgcn_s_barrier();

        // ======== phase 3: (mh=1, nh=0) ========
        stageA(st, 64); stageA(st, 192);
        __builtin_amdgcn_s_barrier();
        __builtin_amdgcn_s_setprio(1);
        #pragma unroll
        for (int mi = 0; mi < 2; mi++)
            #pragma unroll
            for (int ks = 0; ks < 4; ks++)
                acc[2 + mi][0] = __builtin_amdgcn_mfma_i32_32x32x32_i8(
                    af[mi][ks], bf[0][ks], acc[2 + mi][0], 0, 0, 0);
        __builtin_amdgcn_s_setprio(0);
        __builtin_amdgcn_s_barrier();
    }

    // ---- epilogue: per-row max over this block's 256 columns ----
    // C layout (32x32): col = n-tile*32 + cl; row = (reg&3)+8*(reg>>2)+4*hi
    float iny[2];
    #pragma unroll
    for (int ni = 0; ni < 2; ni++)
        iny[ni] = inv_ny[n0 + wc * 64 + ni * 32 + cl] * INV_QS2;

    #pragma unroll
    for (int mi = 0; mi < 4; mi++) {
        #pragma unroll
        for (int reg = 0; reg < 16; reg++) {
            float v = fmaxf((float)acc[mi][0][reg] * iny[0],
                            (float)acc[mi][1][reg] * iny[1]);
            v = fmaxf(v, __shfl_xor(v, 1));
            v = fmaxf(v, __shfl_xor(v, 2));
            v = fmaxf(v, __shfl_xor(v, 4));
            v = fmaxf(v, __shfl_xor(v, 8));
            v = fmaxf(v, __shfl_xor(v, 16));
            if (cl == 0) {
                int row = m0 + wr * 128 + mi * 32 + (reg & 3) + 8 * (reg >> 2) + 4 * hi;
                atomicMax(rowmax_u + row, f2u_ord(v));
            }
        }
    }
}

// ================= fallback path (f32-direct, used only if ws too small) ====
__device__ inline short bfbits(float x) {
    __hip_bfloat16 h = __float2bfloat16(x);
    return __builtin_bit_cast(short, h);
}
__device__ inline short8 pack8(const float4 u, const float4 v) {
    short8 r;
    r[0] = bfbits(u.x); r[1] = bfbits(u.y); r[2] = bfbits(u.z); r[3] = bfbits(u.w);
    r[4] = bfbits(v.x); r[5] = bfbits(v.y); r[6] = bfbits(v.z); r[7] = bfbits(v.w);
    return r;
}

__global__ __launch_bounds__(256) void prep_kernel(
    const float* __restrict__ ex, const float* __restrict__ ey,
    float* __restrict__ inv_nx, float* __restrict__ inv_ny,
    unsigned int* __restrict__ rowmax_u) {
    const int tid  = threadIdx.x;
    const int wave = tid >> 6, lane = tid & 63;
    const int row  = blockIdx.x * 4 + wave;
    if (blockIdx.y == 0) {
        int idx = blockIdx.x * 256 + tid;
        if (idx < NX) rowmax_u[idx] = 0u;
    }
    const float* src = (blockIdx.y == 0) ? ex : ey;
    float* dst       = (blockIdx.y == 0) ? inv_nx : inv_ny;
    const float4* p = reinterpret_cast<const float4*>(src + (size_t)row * KD) + lane * 2;
    float4 v0 = p[0], v1 = p[1];
    float s = v0.x*v0.x + v0.y*v0.y + v0.z*v0.z + v0.w*v0.w
            + v1.x*v1.x + v1.y*v1.y + v1.z*v1.z + v1.w*v1.w;
    #pragma unroll
    for (int off = 32; off; off >>= 1) s += __shfl_xor(s, off);
    if (lane == 0) dst[row] = 1.0f / sqrtf(s);
}

__global__ __launch_bounds__(256) void gemmmax_f32_kernel(
    const float* __restrict__ ex, const float* __restrict__ ey,
    const float* __restrict__ inv_ny, unsigned int* __restrict__ rowmax_u) {
    __shared__ short As[128 * 32];
    __shared__ short Bs[128 * 32];
    const int tid  = threadIdx.x;
    const int lane = tid & 63;
    const int wid  = tid >> 6;
    const int wr   = wid >> 1, wc = wid & 1;
    const int m0   = blockIdx.x * 128;
    const int n0   = blockIdx.y * 128;
    const int srow = tid >> 1;
    const int sseg = tid & 1;
    const int sfz  = ((srow >> 1) & 3) << 4;

    floatx4 acc[4][4];
    #pragma unroll
    for (int mi = 0; mi < 4; mi++)
        #pragma unroll
        for (int ni = 0; ni < 4; ni++)
            acc[mi][ni] = (floatx4){0.f, 0.f, 0.f, 0.f};
    const int ksub  = lane >> 4;
    const int rlane = lane & 15;

    for (int k0 = 0; k0 < KD; k0 += 32) {
        const float4* ga = reinterpret_cast<const float4*>(
            ex + (size_t)(m0 + srow) * KD + k0 + sseg * 16);
        const float4* gb = reinterpret_cast<const float4*>(
            ey + (size_t)(n0 + srow) * KD + k0 + sseg * 16);
        float4 a0 = ga[0], a1 = ga[1], a2 = ga[2], a3 = ga[3];
        float4 b0 = gb[0], b1 = gb[1], b2 = gb[2], b3 = gb[3];
        __syncthreads();
        {
            char* ab = (char*)As + srow * 64;
            char* bb = (char*)Bs + srow * 64;
            *reinterpret_cast<short8*>(ab + ((sseg * 32     ) ^ sfz)) = pack8(a0, a1);
            *reinterpret_cast<short8*>(ab + ((sseg * 32 + 16) ^ sfz)) = pack8(a2, a3);
            *reinterpret_cast<short8*>(bb + ((sseg * 32     ) ^ sfz)) = pack8(b0, b1);
            *reinterpret_cast<short8*>(bb + ((sseg * 32 + 16) ^ sfz)) = pack8(b2, b3);
        }
        __syncthreads();
        short8 afrag[4], bfrag[4];
        #pragma unroll
        for (int mi = 0; mi < 4; mi++) {
            int row = wr * 64 + mi * 16 + rlane;
            int fz  = ((row >> 1) & 3) << 4;
            afrag[mi] = *reinterpret_cast<const short8*>(
                (const char*)As + row * 64 + ((ksub * 16) ^ fz));
        }
        #pragma unroll
        for (int ni = 0; ni < 4; ni++) {
            int col = wc * 64 + ni * 16 + rlane;
            int fz  = ((col >> 1) & 3) << 4;
            bfrag[ni] = *reinterpret_cast<const short8*>(
                (const char*)Bs + col * 64 + ((ksub * 16) ^ fz));
        }
        #pragma unroll
        for (int mi = 0; mi < 4; mi++)
            #pragma unroll
            for (int ni = 0; ni < 4; ni++)
                acc[mi][ni] = __builtin_amdgcn_mfma_f32_16x16x32_bf16(
                    afrag[mi], bfrag[ni], acc[mi][ni], 0, 0, 0);
    }
    float iny[4];
    #pragma unroll
    for (int ni = 0; ni < 4; ni++)
        iny[ni] = inv_ny[n0 + wc * 64 + ni * 16 + rlane];
    #pragma unroll
    for (int mi = 0; mi < 4; mi++) {
        #pragma unroll
        for (int reg = 0; reg < 4; reg++) {
            float v = -INFINITY;
            #pragma unroll
            for (int ni = 0; ni < 4; ni++)
                v = fmaxf(v, acc[mi][ni][reg] * iny[ni]);
            v = fmaxf(v, __shfl_xor(v, 1));
            v = fmaxf(v, __shfl_xor(v, 2));
            v = fmaxf(v, __shfl_xor(v, 4));
            v = fmaxf(v, __shfl_xor(v, 8));
            if (rlane == 0) {
                int row = m0 + wr * 64 + mi * 16 + ksub * 4 + reg;
                atomicMax(rowmax_u + row, f2u_ord(v));
            }
        }
    }
}

// ================= kernel 2: cmax -> HalfNormal log-prob -> sum =============
__global__ __launch_bounds__(1024) void finalize_kernel(
    const unsigned int* __restrict__ rowmax_u, const float* __restrict__ inv_nx,
    float* __restrict__ out) {
    __shared__ float red[16];
    const int tid = threadIdx.x;
    float s = 0.f;
    for (int i = tid; i < NX; i += 1024) {
        float cmax = u2f_ord(rowmax_u[i]) * inv_nx[i];
        float x = 1.0f - cmax;
        s += x * x;
    }
    #pragma unroll
    for (int off = 32; off; off >>= 1) s += __shfl_xor(s, off);
    if ((tid & 63) == 0) red[tid >> 6] = s;
    __syncthreads();
    if (tid < 16) {
        float t = red[tid];
        t += __shfl_xor(t, 8);
        t += __shfl_xor(t, 4);
        t += __shfl_xor(t, 2);
        t += __shfl_xor(t, 1);
        if (tid == 0) {
            const float log_const = logf(2.0f) - logf(0.3f) - 0.5f * logf(2.0f * (float)M_PI);
            out[0] = (float)NX * log_const - t * (1.0f / (2.0f * 0.3f * 0.3f));
        }
    }
}

extern "C" void kernel_launch(void* const* d_in, const int* in_sizes, int n_in,
                              void* d_out, int out_size, void* d_ws, size_t ws_size,
                              hipStream_t stream) {
    const float* ex = (const float*)d_in[0];
    const float* ey = (const float*)d_in[1];
    float* inv_nx        = (float*)d_ws;
    float* inv_ny        = inv_nx + NX;
    unsigned int* rowmax = (unsigned int*)(inv_ny + NY);
    float* out           = (float*)d_out;

    const size_t head = (size_t)(NX + NY + NX) * 4;          // norms + rowmax
    const size_t need = head + (size_t)(NX + NY) * KD;       // + i8 copies

    if (ws_size >= need) {
        char* exq = (char*)d_ws + head;
        char* eyq = exq + (size_t)NX * KD;
        convert_kernel<<<dim3((NX + NY) / 4), 256, 0, stream>>>(
            ex, ey, exq, eyq, inv_nx, inv_ny, rowmax);
        gemm8p_i8_kernel<<<dim3(NX / 256, NY / 256), 512, 0, stream>>>(
            exq, eyq, inv_ny, rowmax);
    } else {
        prep_kernel<<<dim3(NX / 4, 2), 256, 0, stream>>>(ex, ey, inv_nx, inv_ny, rowmax);
        gemmmax_f32_kernel<<<dim3(NX / 128, NY / 128), 256, 0, stream>>>(
            ex, ey, inv_ny, rowmax);
    }
    finalize_kernel<<<1, 1024, 0, stream>>>(rowmax, inv_nx, out);
}

// Round 6
// 76.404 us; speedup vs baseline: 1.4582x; 1.4582x over previous
//
#include <hip/hip_runtime.h>
#include <hip/hip_bf16.h>
#include <math.h>

typedef short short8  __attribute__((ext_vector_type(8)));
typedef float floatx4 __attribute__((ext_vector_type(4)));
typedef char  charx8  __attribute__((ext_vector_type(8)));
typedef int   intx4   __attribute__((ext_vector_type(4)));

#define NX 8192
#define NY 8192
#define KD 512
#define QS 26.0f                   // i8 quant scale
#define INV_QS2 (1.0f / (26.0f * 26.0f))
#define TILEB (256 * 128)          // one K-tile (BK=128 i8) = 32 KB

// ---- order-preserving float<->uint transform for atomicMax on floats ----
__device__ inline unsigned int f2u_ord(float x) {
    unsigned int u = __float_as_uint(x);
    return (u & 0x80000000u) ? ~u : (u | 0x80000000u);
}
__device__ inline float u2f_ord(unsigned int u) {
    return (u & 0x80000000u) ? __uint_as_float(u & 0x7fffffffu)
                             : __uint_as_float(~u);
}

__device__ inline char q8(float x) {
    float xs = fmaxf(-127.0f, fminf(127.0f, x * QS));
    return (char)(int)rintf(xs);
}
__device__ inline charx8 qpack8(const float4 u, const float4 v) {
    charx8 r;
    r[0] = q8(u.x); r[1] = q8(u.y); r[2] = q8(u.z); r[3] = q8(u.w);
    r[4] = q8(v.x); r[5] = q8(v.y); r[6] = q8(v.z); r[7] = q8(v.w);
    return r;
}

__device__ __forceinline__ void gload_lds16(const void* g, void* l) {
    __builtin_amdgcn_global_load_lds(
        (const __attribute__((address_space(1))) unsigned int*)g,
        (__attribute__((address_space(3))) unsigned int*)l, 16, 0, 0);
}

// ================= kernel 0: f32 -> i8 quantize + inv-norms + rowmax init ===
__global__ __launch_bounds__(256) void convert_kernel(
    const float* __restrict__ ex, const float* __restrict__ ey,
    char* __restrict__ exq, char* __restrict__ eyq,
    float* __restrict__ inv_nx, float* __restrict__ inv_ny,
    unsigned int* __restrict__ rowmax_u) {
    const int tid  = threadIdx.x;
    const int wid  = tid >> 6, lane = tid & 63;
    const int gr   = blockIdx.x * 4 + wid;          // 0..16383

    const bool isx = (gr < NX);
    const int row  = isx ? gr : gr - NX;
    const float* src = isx ? ex : ey;
    char* dst        = isx ? exq : eyq;
    float* inv       = isx ? inv_nx : inv_ny;

    const float4* p = reinterpret_cast<const float4*>(src + (size_t)row * KD) + lane * 2;
    float4 v0 = p[0], v1 = p[1];
    *reinterpret_cast<charx8*>(dst + (size_t)row * KD + lane * 8) = qpack8(v0, v1);

    float s = v0.x*v0.x + v0.y*v0.y + v0.z*v0.z + v0.w*v0.w
            + v1.x*v1.x + v1.y*v1.y + v1.z*v1.z + v1.w*v1.w;
    #pragma unroll
    for (int off = 32; off; off >>= 1) s += __shfl_xor(s, off);
    if (lane == 0) {
        inv[row] = 1.0f / sqrtf(s);
        if (isx) rowmax_u[row] = 0u;    // below transform of any real float
    }
}

// ================= kernel 1: 256x256 i8 MFMA GEMM (BK=128, 16x16x64) ========
// Exact round-4 schedule, i8 types. 8 waves (2M x 4N), per-wave 128x64 out
// = 8x4 tiles of 16x16. Double-buffered 128 KiB LDS; global_load_lds with
// counted vmcnt (T3+T4); XOR chunk swizzle via pre-swizzled source (T2);
// setprio around MFMA clusters (T5). 16-lane fragment pattern (row=lane&15,
// chunk=ks*4+g) measured conflict-free in round 4.
__global__ __launch_bounds__(512, 2) void gemm8p_i8_kernel(
    const char* __restrict__ exq, const char* __restrict__ eyq,
    const float* __restrict__ inv_ny, unsigned int* __restrict__ rowmax_u) {
    __shared__ char As[2][TILEB];   // [buf][row*128 + kbyte], row stride 128 B
    __shared__ char Bs[2][TILEB];

    const int tid   = threadIdx.x;
    const int lane  = tid & 63;
    const int wid   = tid >> 6;     // 0..7
    const int wr    = wid >> 2;     // 0..1 (M)
    const int wc    = wid & 3;      // 0..3 (N)
    const int g     = lane >> 4;    // 0..3 (k-group within 64-B k-step)
    const int rlane = lane & 15;
    const int m0    = blockIdx.x * 256;
    const int n0    = blockIdx.y * 256;

    // staging map: 512 threads x 16B = 64 rows (of 128 B) per issue
    const int sr  = tid >> 3;       // 0..63 row within quarter
    const int sc  = tid & 7;        // chunk 0..7
    const int scs = sc ^ (sr & 7);  // pre-swizzled global source chunk

    intx4 acc[8][4];
    #pragma unroll
    for (int i = 0; i < 8; i++)
        #pragma unroll
        for (int j = 0; j < 4; j++)
            acc[i][j] = (intx4){0, 0, 0, 0};

    intx4 af[4][2];   // current m-half: 4 M-tiles x 2 k-steps
    intx4 bf[4][2];   // all 4 n-positions x 2 k-steps (persist per K-tile)

    auto stageA = [&](int st, int R0) {
        const char* src = exq + (size_t)(m0 + R0 + sr) * KD + (st << 7) + (scs << 4);
        gload_lds16(src, &As[st & 1][R0 * 128 + tid * 16]);
    };
    auto stageB = [&](int st, int R0) {
        const char* src = eyq + (size_t)(n0 + R0 + sr) * KD + (st << 7) + (scs << 4);
        gload_lds16(src, &Bs[st & 1][R0 * 128 + tid * 16]);
    };
    // fragment read: chunk = ks*4+g, same involution as staging
    auto rdA = [&](int cur, int row, int chunk) -> intx4 {
        return *reinterpret_cast<const intx4*>(
            &As[cur][row * 128 + ((chunk ^ (row & 7)) << 4)]);
    };
    auto rdB = [&](int cur, int row, int chunk) -> intx4 {
        return *reinterpret_cast<const intx4*>(
            &Bs[cur][row * 128 + ((chunk ^ (row & 7)) << 4)]);
    };

    // prologue: stage tile 0 (order: B0,B64,B128,B192,A0,A128,A64,A192)
    stageB(0, 0);  stageB(0, 64); stageB(0, 128); stageB(0, 192);
    stageA(0, 0);  stageA(0, 128);                 // needed at phase 0
    stageA(0, 64); stageA(0, 192);                 // needed at phase 2

    for (int t = 0; t < 4; ++t) {                  // KD/128 = 4 K-tiles
        const int cur = t & 1;
        const int st  = (t + 1) & 3;   // wraps at t=3: wasted re-stage of
                                       // tile 0 keeps vmcnt counts uniform
        // ---- K-tile boundary: all but the 2 newest (A64,A192) done ----
        asm volatile("s_waitcnt vmcnt(2)" ::: "memory");
        __builtin_amdgcn_s_barrier();

        // ======== phase 0: quadrant (mh=0, nh=0) ========
        #pragma unroll
        for (int mi = 0; mi < 4; mi++) {
            int arow = wr * 128 + mi * 16 + rlane;
            #pragma unroll
            for (int ks = 0; ks < 2; ks++) af[mi][ks] = rdA(cur, arow, ks * 4 + g);
        }
        #pragma unroll
        for (int ni = 0; ni < 2; ni++) {
            int brow = wc * 64 + ni * 16 + rlane;
            #pragma unroll
            for (int ks = 0; ks < 2; ks++) bf[ni][ks] = rdB(cur, brow, ks * 4 + g);
        }
        stageB(st, 0); stageB(st, 64);
        __builtin_amdgcn_s_barrier();
        __builtin_amdgcn_s_setprio(1);
        #pragma unroll
        for (int mi = 0; mi < 4; mi++)
            #pragma unroll
            for (int ni = 0; ni < 2; ni++)
                #pragma unroll
                for (int ks = 0; ks < 2; ks++)
                    acc[mi][ni] = __builtin_amdgcn_mfma_i32_16x16x64_i8(
                        af[mi][ks], bf[ni][ks], acc[mi][ni], 0, 0, 0);
        __builtin_amdgcn_s_setprio(0);
        __builtin_amdgcn_s_barrier();

        // ======== phase 1: quadrant (mh=0, nh=1) ========
        #pragma unroll
        for (int ni = 2; ni < 4; ni++) {
            int brow = wc * 64 + ni * 16 + rlane;
            #pragma unroll
            for (int ks = 0; ks < 2; ks++) bf[ni][ks] = rdB(cur, brow, ks * 4 + g);
        }
        stageB(st, 128); stageB(st, 192);
        asm volatile("s_waitcnt vmcnt(4)" ::: "memory");  // drain cur's A64,A192
        __builtin_amdgcn_s_barrier();
        __builtin_amdgcn_s_setprio(1);
        #pragma unroll
        for (int mi = 0; mi < 4; mi++)
            #pragma unroll
            for (int ni = 2; ni < 4; ni++)
                #pragma unroll
                for (int ks = 0; ks < 2; ks++)
                    acc[mi][ni] = __builtin_amdgcn_mfma_i32_16x16x64_i8(
                        af[mi][ks], bf[ni][ks], acc[mi][ni], 0, 0, 0);
        __builtin_amdgcn_s_setprio(0);
        __builtin_amdgcn_s_barrier();

        // ======== phase 2: quadrant (mh=1, nh=1) ========
        #pragma unroll
        for (int mi = 0; mi < 4; mi++) {
            int arow = wr * 128 + 64 + mi * 16 + rlane;
            #pragma unroll
            for (int ks = 0; ks < 2; ks++) af[mi][ks] = rdA(cur, arow, ks * 4 + g);
        }
        stageA(st, 0); stageA(st, 128);
        __builtin_amdgcn_s_barrier();
        __builtin_amdgcn_s_setprio(1);
        #pragma unroll
        for (int mi = 0; mi < 4; mi++)
            #pragma unroll
            for (int ni = 2; ni < 4; ni++)
                #pragma unroll
                for (int ks = 0; ks < 2; ks++)
                    acc[4 + mi][ni] = __builtin_amdgcn_mfma_i32_16x16x64_i8(
                        af[mi][ks], bf[ni][ks], acc[4 + mi][ni], 0, 0, 0);
        __builtin_amdgcn_s_setprio(0);
        __builtin_amdgcn_s_barrier();

        // ======== phase 3: quadrant (mh=1, nh=0) ========
        stageA(st, 64); stageA(st, 192);
        __builtin_amdgcn_s_barrier();
        __builtin_amdgcn_s_setprio(1);
        #pragma unroll
        for (int mi = 0; mi < 4; mi++)
            #pragma unroll
            for (int ni = 0; ni < 2; ni++)
                #pragma unroll
                for (int ks = 0; ks < 2; ks++)
                    acc[4 + mi][ni] = __builtin_amdgcn_mfma_i32_16x16x64_i8(
                        af[mi][ks], bf[ni][ks], acc[4 + mi][ni], 0, 0, 0);
        __builtin_amdgcn_s_setprio(0);
        __builtin_amdgcn_s_barrier();
    }

    // ---- epilogue: per-row max over this block's 256 columns ----
    // C layout (16x16): col = lane&15, row = g*4 + reg (dtype-independent)
    float iny[4];
    #pragma unroll
    for (int ni = 0; ni < 4; ni++)
        iny[ni] = inv_ny[n0 + wc * 64 + ni * 16 + rlane] * INV_QS2;

    #pragma unroll
    for (int ai = 0; ai < 8; ai++) {
        const int rbase = m0 + wr * 128 + (ai >> 2) * 64 + (ai & 3) * 16 + g * 4;
        #pragma unroll
        for (int reg = 0; reg < 4; reg++) {
            float v = -INFINITY;
            #pragma unroll
            for (int ni = 0; ni < 4; ni++)
                v = fmaxf(v, (float)acc[ai][ni][reg] * iny[ni]);
            v = fmaxf(v, __shfl_xor(v, 1));
            v = fmaxf(v, __shfl_xor(v, 2));
            v = fmaxf(v, __shfl_xor(v, 4));
            v = fmaxf(v, __shfl_xor(v, 8));
            if (rlane == 0)
                atomicMax(rowmax_u + rbase + reg, f2u_ord(v));
        }
    }
}

// ================= fallback path (f32-direct, used only if ws too small) ====
__device__ inline short bfbits(float x) {
    __hip_bfloat16 h = __float2bfloat16(x);
    return __builtin_bit_cast(short, h);
}
__device__ inline short8 pack8(const float4 u, const float4 v) {
    short8 r;
    r[0] = bfbits(u.x); r[1] = bfbits(u.y); r[2] = bfbits(u.z); r[3] = bfbits(u.w);
    r[4] = bfbits(v.x); r[5] = bfbits(v.y); r[6] = bfbits(v.z); r[7] = bfbits(v.w);
    return r;
}

__global__ __launch_bounds__(256) void prep_kernel(
    const float* __restrict__ ex, const float* __restrict__ ey,
    float* __restrict__ inv_nx, float* __restrict__ inv_ny,
    unsigned int* __restrict__ rowmax_u) {
    const int tid  = threadIdx.x;
    const int wave = tid >> 6, lane = tid & 63;
    const int row  = blockIdx.x * 4 + wave;
    if (blockIdx.y == 0) {
        int idx = blockIdx.x * 256 + tid;
        if (idx < NX) rowmax_u[idx] = 0u;
    }
    const float* src = (blockIdx.y == 0) ? ex : ey;
    float* dst       = (blockIdx.y == 0) ? inv_nx : inv_ny;
    const float4* p = reinterpret_cast<const float4*>(src + (size_t)row * KD) + lane * 2;
    float4 v0 = p[0], v1 = p[1];
    float s = v0.x*v0.x + v0.y*v0.y + v0.z*v0.z + v0.w*v0.w
            + v1.x*v1.x + v1.y*v1.y + v1.z*v1.z + v1.w*v1.w;
    #pragma unroll
    for (int off = 32; off; off >>= 1) s += __shfl_xor(s, off);
    if (lane == 0) dst[row] = 1.0f / sqrtf(s);
}

__global__ __launch_bounds__(256) void gemmmax_f32_kernel(
    const float* __restrict__ ex, const float* __restrict__ ey,
    const float* __restrict__ inv_ny, unsigned int* __restrict__ rowmax_u) {
    __shared__ short As[128 * 32];
    __shared__ short Bs[128 * 32];
    const int tid  = threadIdx.x;
    const int lane = tid & 63;
    const int wid  = tid >> 6;
    const int wr   = wid >> 1, wc = wid & 1;
    const int m0   = blockIdx.x * 128;
    const int n0   = blockIdx.y * 128;
    const int srow = tid >> 1;
    const int sseg = tid & 1;
    const int sfz  = ((srow >> 1) & 3) << 4;

    floatx4 acc[4][4];
    #pragma unroll
    for (int mi = 0; mi < 4; mi++)
        #pragma unroll
        for (int ni = 0; ni < 4; ni++)
            acc[mi][ni] = (floatx4){0.f, 0.f, 0.f, 0.f};
    const int ksub  = lane >> 4;
    const int rlane = lane & 15;

    for (int k0 = 0; k0 < KD; k0 += 32) {
        const float4* ga = reinterpret_cast<const float4*>(
            ex + (size_t)(m0 + srow) * KD + k0 + sseg * 16);
        const float4* gb = reinterpret_cast<const float4*>(
            ey + (size_t)(n0 + srow) * KD + k0 + sseg * 16);
        float4 a0 = ga[0], a1 = ga[1], a2 = ga[2], a3 = ga[3];
        float4 b0 = gb[0], b1 = gb[1], b2 = gb[2], b3 = gb[3];
        __syncthreads();
        {
            char* ab = (char*)As + srow * 64;
            char* bb = (char*)Bs + srow * 64;
            *reinterpret_cast<short8*>(ab + ((sseg * 32     ) ^ sfz)) = pack8(a0, a1);
            *reinterpret_cast<short8*>(ab + ((sseg * 32 + 16) ^ sfz)) = pack8(a2, a3);
            *reinterpret_cast<short8*>(bb + ((sseg * 32     ) ^ sfz)) = pack8(b0, b1);
            *reinterpret_cast<short8*>(bb + ((sseg * 32 + 16) ^ sfz)) = pack8(b2, b3);
        }
        __syncthreads();
        short8 afrag[4], bfrag[4];
        #pragma unroll
        for (int mi = 0; mi < 4; mi++) {
            int row = wr * 64 + mi * 16 + rlane;
            int fz  = ((row >> 1) & 3) << 4;
            afrag[mi] = *reinterpret_cast<const short8*>(
                (const char*)As + row * 64 + ((ksub * 16) ^ fz));
        }
        #pragma unroll
        for (int ni = 0; ni < 4; ni++) {
            int col = wc * 64 + ni * 16 + rlane;
            int fz  = ((col >> 1) & 3) << 4;
            bfrag[ni] = *reinterpret_cast<const short8*>(
                (const char*)Bs + col * 64 + ((ksub * 16) ^ fz));
        }
        #pragma unroll
        for (int mi = 0; mi < 4; mi++)
            #pragma unroll
            for (int ni = 0; ni < 4; ni++)
                acc[mi][ni] = __builtin_amdgcn_mfma_f32_16x16x32_bf16(
                    afrag[mi], bfrag[ni], acc[mi][ni], 0, 0, 0);
    }
    float iny[4];
    #pragma unroll
    for (int ni = 0; ni < 4; ni++)
        iny[ni] = inv_ny[n0 + wc * 64 + ni * 16 + rlane];
    #pragma unroll
    for (int mi = 0; mi < 4; mi++) {
        #pragma unroll
        for (int reg = 0; reg < 4; reg++) {
            float v = -INFINITY;
            #pragma unroll
            for (int ni = 0; ni < 4; ni++)
                v = fmaxf(v, acc[mi][ni][reg] * iny[ni]);
            v = fmaxf(v, __shfl_xor(v, 1));
            v = fmaxf(v, __shfl_xor(v, 2));
            v = fmaxf(v, __shfl_xor(v, 4));
            v = fmaxf(v, __shfl_xor(v, 8));
            if (rlane == 0) {
                int row = m0 + wr * 64 + mi * 16 + ksub * 4 + reg;
                atomicMax(rowmax_u + row, f2u_ord(v));
            }
        }
    }
}

// ================= kernel 2: cmax -> HalfNormal log-prob -> sum =============
__global__ __launch_bounds__(1024) void finalize_kernel(
    const unsigned int* __restrict__ rowmax_u, const float* __restrict__ inv_nx,
    float* __restrict__ out) {
    __shared__ float red[16];
    const int tid = threadIdx.x;
    float s = 0.f;
    for (int i = tid; i < NX; i += 1024) {
        float cmax = u2f_ord(rowmax_u[i]) * inv_nx[i];
        float x = 1.0f - cmax;
        s += x * x;
    }
    #pragma unroll
    for (int off = 32; off; off >>= 1) s += __shfl_xor(s, off);
    if ((tid & 63) == 0) red[tid >> 6] = s;
    __syncthreads();
    if (tid < 16) {
        float t = red[tid];
        t += __shfl_xor(t, 8);
        t += __shfl_xor(t, 4);
        t += __shfl_xor(t, 2);
        t += __shfl_xor(t, 1);
        if (tid == 0) {
            const float log_const = logf(2.0f) - logf(0.3f) - 0.5f * logf(2.0f * (float)M_PI);
            out[0] = (float)NX * log_const - t * (1.0f / (2.0f * 0.3f * 0.3f));
        }
    }
}

extern "C" void kernel_launch(void* const* d_in, const int* in_sizes, int n_in,
                              void* d_out, int out_size, void* d_ws, size_t ws_size,
                              hipStream_t stream) {
    const float* ex = (const float*)d_in[0];
    const float* ey = (const float*)d_in[1];
    float* inv_nx        = (float*)d_ws;
    float* inv_ny        = inv_nx + NX;
    unsigned int* rowmax = (unsigned int*)(inv_ny + NY);
    float* out           = (float*)d_out;

    const size_t head = (size_t)(NX + NY + NX) * 4;          // norms + rowmax
    const size_t need = head + (size_t)(NX + NY) * KD;       // + i8 copies

    if (ws_size >= need) {
        char* exq = (char*)d_ws + head;
        char* eyq = exq + (size_t)NX * KD;
        convert_kernel<<<dim3((NX + NY) / 4), 256, 0, stream>>>(
            ex, ey, exq, eyq, inv_nx, inv_ny, rowmax);
        gemm8p_i8_kernel<<<dim3(NX / 256, NY / 256), 512, 0, stream>>>(
            exq, eyq, inv_ny, rowmax);
    } else {
        prep_kernel<<<dim3(NX / 4, 2), 256, 0, stream>>>(ex, ey, inv_nx, inv_ny, rowmax);
        gemmmax_f32_kernel<<<dim3(NX / 128, NY / 128), 256, 0, stream>>>(
            ex, ey, inv_ny, rowmax);
    }
    finalize_kernel<<<1, 1024, 0, stream>>>(rowmax, inv_nx, out);
}

// Round 8
// 63.903 us; speedup vs baseline: 1.7435x; 1.1956x over previous
//
#include <hip/hip_runtime.h>
#include <hip/hip_bf16.h>
#include <math.h>

typedef short short8  __attribute__((ext_vector_type(8)));
typedef float floatx4 __attribute__((ext_vector_type(4)));
typedef char  charx8  __attribute__((ext_vector_type(8)));
typedef int   intx4   __attribute__((ext_vector_type(4)));

#define NX 8192
#define NY 8192
#define KD 512
#define QS 26.0f                   // i8 quant scale
#define INV_QS2 (1.0f / (26.0f * 26.0f))
#define BM 128
#define BN 256
#define BK 64                      // bytes per row per K-tile (i8)

// ---- order-preserving float<->uint transform for atomicMax on floats ----
__device__ inline unsigned int f2u_ord(float x) {
    unsigned int u = __float_as_uint(x);
    return (u & 0x80000000u) ? ~u : (u | 0x80000000u);
}
__device__ inline float u2f_ord(unsigned int u) {
    return (u & 0x80000000u) ? __uint_as_float(u & 0x7fffffffu)
                             : __uint_as_float(~u);
}

__device__ inline char q8(float x) {
    float xs = fmaxf(-127.0f, fminf(127.0f, x * QS));
    return (char)(int)rintf(xs);
}
__device__ inline charx8 qpack8(const float4 u, const float4 v) {
    charx8 r;
    r[0] = q8(u.x); r[1] = q8(u.y); r[2] = q8(u.z); r[3] = q8(u.w);
    r[4] = q8(v.x); r[5] = q8(v.y); r[6] = q8(v.z); r[7] = q8(v.w);
    return r;
}

__device__ __forceinline__ void gload_lds16(const void* g, void* l) {
    __builtin_amdgcn_global_load_lds(
        (const __attribute__((address_space(1))) unsigned int*)g,
        (__attribute__((address_space(3))) unsigned int*)l, 16, 0, 0);
}

// ================= kernel 0: f32 -> i8 quantize + inv-norms + rowmax init ===
__global__ __launch_bounds__(256) void convert_kernel(
    const float* __restrict__ ex, const float* __restrict__ ey,
    char* __restrict__ exq, char* __restrict__ eyq,
    float* __restrict__ inv_nx, float* __restrict__ inv_ny,
    unsigned int* __restrict__ rowmax_u) {
    const int tid  = threadIdx.x;
    const int wid  = tid >> 6, lane = tid & 63;
    const int gr   = blockIdx.x * 4 + wid;          // 0..16383

    const bool isx = (gr < NX);
    const int row  = isx ? gr : gr - NX;
    const float* src = isx ? ex : ey;
    char* dst        = isx ? exq : eyq;
    float* inv       = isx ? inv_nx : inv_ny;

    const float4* p = reinterpret_cast<const float4*>(src + (size_t)row * KD) + lane * 2;
    float4 v0 = p[0], v1 = p[1];
    *reinterpret_cast<charx8*>(dst + (size_t)row * KD + lane * 8) = qpack8(v0, v1);

    float s = v0.x*v0.x + v0.y*v0.y + v0.z*v0.z + v0.w*v0.w
            + v1.x*v1.x + v1.y*v1.y + v1.z*v1.z + v1.w*v1.w;
    #pragma unroll
    for (int off = 32; off; off >>= 1) s += __shfl_xor(s, off);
    if (lane == 0) {
        inv[row] = 1.0f / sqrtf(s);
        if (isx) rowmax_u[row] = 0u;    // below transform of any real float
    }
}

// ================= kernel 1: 128x256 i8 MFMA GEMM (BK=64, co-resident) ======
// 8 waves (2M x 4N), per-wave 64x64 out = 4x4 tiles of 16x16 (acc = 64 regs).
// 48 KB dbuf LDS + 2 KB reduce -> 2 blocks/CU; __launch_bounds__(512,4)
// caps regs at 128 so 16 waves/CU co-reside and fill barrier stalls (m114).
// One vmcnt(0)+barrier per K-tile (only cross-wave hazard is the buffer
// handoff; per-wave vmcnt drains own stages before the barrier).
// Swizzle for 64-B rows: chunk ^= (row>>1)&3 -> 2-way per quarter-wave (free).
__global__ __launch_bounds__(512, 4) void gemm_i8_kernel(
    const char* __restrict__ exq, const char* __restrict__ eyq,
    const float* __restrict__ inv_ny, unsigned int* __restrict__ rowmax_u) {
    __shared__ char As[2][BM * BK];   // 2 x 8 KB
    __shared__ char Bs[2][BN * BK];   // 2 x 16 KB
    __shared__ float red[BM][4];      // cross-wave-col row-max reduce

    const int tid   = threadIdx.x;
    const int lane  = tid & 63;
    const int wid   = tid >> 6;     // 0..7
    const int wr    = wid >> 2;     // 0..1 (M)
    const int wc    = wid & 3;      // 0..3 (N)
    const int g     = lane >> 4;    // 0..3
    const int rlane = lane & 15;
    const int m0    = blockIdx.x * BM;
    const int n0    = blockIdx.y * BN;

    // staging map: 512 threads x 16 B = 8 KB = 128 rows of 64 B per issue
    const int sr  = tid >> 2;              // 0..127 row within issue
    const int sc  = tid & 3;               // chunk 0..3
    const int scs = sc ^ ((sr >> 1) & 3);  // pre-swizzled global source chunk

    intx4 acc[4][4];
    #pragma unroll
    for (int i = 0; i < 4; i++)
        #pragma unroll
        for (int j = 0; j < 4; j++)
            acc[i][j] = (intx4){0, 0, 0, 0};

    const char* gA  = exq + (size_t)(m0 + sr) * KD + (scs << 4);
    const char* gB0 = eyq + (size_t)(n0 + sr) * KD + (scs << 4);
    const char* gB1 = gB0 + (size_t)128 * KD;

    auto stage = [&](int t) {
        const int b = t & 1;
        gload_lds16(gA  + (t << 6), &As[b][tid * 16]);
        gload_lds16(gB0 + (t << 6), &Bs[b][tid * 16]);
        gload_lds16(gB1 + (t << 6), &Bs[b][128 * BK + tid * 16]);
    };
    auto rd = [&](const char* base, int row, int gg) -> intx4 {
        return *reinterpret_cast<const intx4*>(
            base + row * BK + (((gg ^ ((row >> 1) & 3))) << 4));
    };

    stage(0);

    for (int t = 0; t < 8; ++t) {           // KD/BK = 8 K-tiles
        // boundary: own stages drained by every wave, then all waves agree
        asm volatile("s_waitcnt vmcnt(0)" ::: "memory");
        __builtin_amdgcn_s_barrier();
        asm volatile("" ::: "memory");

        const char* Ab = As[t & 1];
        const char* Bb = Bs[t & 1];
        intx4 af[4], bf[4];
        #pragma unroll
        for (int ai = 0; ai < 4; ai++)
            af[ai] = rd(Ab, wr * 64 + ai * 16 + rlane, g);
        #pragma unroll
        for (int ni = 0; ni < 4; ni++)
            bf[ni] = rd(Bb, wc * 64 + ni * 16 + rlane, g);

        if (t < 7) stage(t + 1);            // into buf (t+1)&1 — disjoint

        __builtin_amdgcn_s_setprio(1);
        #pragma unroll
        for (int ai = 0; ai < 4; ai++)
            #pragma unroll
            for (int ni = 0; ni < 4; ni++)
                acc[ai][ni] = __builtin_amdgcn_mfma_i32_16x16x64_i8(
                    af[ai], bf[ni], acc[ai][ni], 0, 0, 0);
        __builtin_amdgcn_s_setprio(0);
    }

    // ---- epilogue: per-row max over this block's 256 columns ----
    float iny[4];
    #pragma unroll
    for (int ni = 0; ni < 4; ni++)
        iny[ni] = inv_ny[n0 + wc * 64 + ni * 16 + rlane] * INV_QS2;

    #pragma unroll
    for (int ai = 0; ai < 4; ai++) {
        #pragma unroll
        for (int reg = 0; reg < 4; reg++) {
            float v = -INFINITY;
            #pragma unroll
            for (int ni = 0; ni < 4; ni++)
                v = fmaxf(v, (float)acc[ai][ni][reg] * iny[ni]);
            v = fmaxf(v, __shfl_xor(v, 1));
            v = fmaxf(v, __shfl_xor(v, 2));
            v = fmaxf(v, __shfl_xor(v, 4));
            v = fmaxf(v, __shfl_xor(v, 8));
            if (rlane == 0)
                red[wr * 64 + ai * 16 + g * 4 + reg][wc] = v;
        }
    }
    __syncthreads();
    if (tid < BM) {
        float m = fmaxf(fmaxf(red[tid][0], red[tid][1]),
                        fmaxf(red[tid][2], red[tid][3]));
        atomicMax(rowmax_u + m0 + tid, f2u_ord(m));
    }
}

// ================= fallback path (f32-direct, used only if ws too small) ====
__device__ inline short bfbits(float x) {
    __hip_bfloat16 h = __float2bfloat16(x);
    return __builtin_bit_cast(short, h);
}
__device__ inline short8 pack8(const float4 u, const float4 v) {
    short8 r;
    r[0] = bfbits(u.x); r[1] = bfbits(u.y); r[2] = bfbits(u.z); r[3] = bfbits(u.w);
    r[4] = bfbits(v.x); r[5] = bfbits(v.y); r[6] = bfbits(v.z); r[7] = bfbits(v.w);
    return r;
}

__global__ __launch_bounds__(256) void prep_kernel(
    const float* __restrict__ ex, const float* __restrict__ ey,
    float* __restrict__ inv_nx, float* __restrict__ inv_ny,
    unsigned int* __restrict__ rowmax_u) {
    const int tid  = threadIdx.x;
    const int wave = tid >> 6, lane = tid & 63;
    const int row  = blockIdx.x * 4 + wave;
    if (blockIdx.y == 0) {
        int idx = blockIdx.x * 256 + tid;
        if (idx < NX) rowmax_u[idx] = 0u;
    }
    const float* src = (blockIdx.y == 0) ? ex : ey;
    float* dst       = (blockIdx.y == 0) ? inv_nx : inv_ny;
    const float4* p = reinterpret_cast<const float4*>(src + (size_t)row * KD) + lane * 2;
    float4 v0 = p[0], v1 = p[1];
    float s = v0.x*v0.x + v0.y*v0.y + v0.z*v0.z + v0.w*v0.w
            + v1.x*v1.x + v1.y*v1.y + v1.z*v1.z + v1.w*v1.w;
    #pragma unroll
    for (int off = 32; off; off >>= 1) s += __shfl_xor(s, off);
    if (lane == 0) dst[row] = 1.0f / sqrtf(s);
}

__global__ __launch_bounds__(256) void gemmmax_f32_kernel(
    const float* __restrict__ ex, const float* __restrict__ ey,
    const float* __restrict__ inv_ny, unsigned int* __restrict__ rowmax_u) {
    __shared__ short Asf[128 * 32];
    __shared__ short Bsf[128 * 32];
    const int tid  = threadIdx.x;
    const int lane = tid & 63;
    const int wid  = tid >> 6;
    const int wr   = wid >> 1, wc = wid & 1;
    const int m0   = blockIdx.x * 128;
    const int n0   = blockIdx.y * 128;
    const int srow = tid >> 1;
    const int sseg = tid & 1;
    const int sfz  = ((srow >> 1) & 3) << 4;

    floatx4 acc[4][4];
    #pragma unroll
    for (int mi = 0; mi < 4; mi++)
        #pragma unroll
        for (int ni = 0; ni < 4; ni++)
            acc[mi][ni] = (floatx4){0.f, 0.f, 0.f, 0.f};
    const int ksub  = lane >> 4;
    const int rlane = lane & 15;

    for (int k0 = 0; k0 < KD; k0 += 32) {
        const float4* ga = reinterpret_cast<const float4*>(
            ex + (size_t)(m0 + srow) * KD + k0 + sseg * 16);
        const float4* gb = reinterpret_cast<const float4*>(
            ey + (size_t)(n0 + srow) * KD + k0 + sseg * 16);
        float4 a0 = ga[0], a1 = ga[1], a2 = ga[2], a3 = ga[3];
        float4 b0 = gb[0], b1 = gb[1], b2 = gb[2], b3 = gb[3];
        __syncthreads();
        {
            char* ab = (char*)Asf + srow * 64;
            char* bb = (char*)Bsf + srow * 64;
            *reinterpret_cast<short8*>(ab + ((sseg * 32     ) ^ sfz)) = pack8(a0, a1);
            *reinterpret_cast<short8*>(ab + ((sseg * 32 + 16) ^ sfz)) = pack8(a2, a3);
            *reinterpret_cast<short8*>(bb + ((sseg * 32     ) ^ sfz)) = pack8(b0, b1);
            *reinterpret_cast<short8*>(bb + ((sseg * 32 + 16) ^ sfz)) = pack8(b2, b3);
        }
        __syncthreads();
        short8 afrag[4], bfrag[4];
        #pragma unroll
        for (int mi = 0; mi < 4; mi++) {
            int row = wr * 64 + mi * 16 + rlane;
            int fz  = ((row >> 1) & 3) << 4;
            afrag[mi] = *reinterpret_cast<const short8*>(
                (const char*)Asf + row * 64 + ((ksub * 16) ^ fz));
        }
        #pragma unroll
        for (int ni = 0; ni < 4; ni++) {
            int col = wc * 64 + ni * 16 + rlane;
            int fz  = ((col >> 1) & 3) << 4;
            bfrag[ni] = *reinterpret_cast<const short8*>(
                (const char*)Bsf + col * 64 + ((ksub * 16) ^ fz));
        }
        #pragma unroll
        for (int mi = 0; mi < 4; mi++)
            #pragma unroll
            for (int ni = 0; ni < 4; ni++)
                acc[mi][ni] = __builtin_amdgcn_mfma_f32_16x16x32_bf16(
                    afrag[mi], bfrag[ni], acc[mi][ni], 0, 0, 0);
    }
    float iny[4];
    #pragma unroll
    for (int ni = 0; ni < 4; ni++)
        iny[ni] = inv_ny[n0 + wc * 64 + ni * 16 + rlane];
    #pragma unroll
    for (int mi = 0; mi < 4; mi++) {
        #pragma unroll
        for (int reg = 0; reg < 4; reg++) {
            float v = -INFINITY;
            #pragma unroll
            for (int ni = 0; ni < 4; ni++)
                v = fmaxf(v, acc[mi][ni][reg] * iny[ni]);
            v = fmaxf(v, __shfl_xor(v, 1));
            v = fmaxf(v, __shfl_xor(v, 2));
            v = fmaxf(v, __shfl_xor(v, 4));
            v = fmaxf(v, __shfl_xor(v, 8));
            if (rlane == 0) {
                int row = m0 + wr * 64 + mi * 16 + ksub * 4 + reg;
                atomicMax(rowmax_u + row, f2u_ord(v));
            }
        }
    }
}

// ================= kernel 2: cmax -> HalfNormal log-prob -> sum =============
__global__ __launch_bounds__(1024) void finalize_kernel(
    const unsigned int* __restrict__ rowmax_u, const float* __restrict__ inv_nx,
    float* __restrict__ out) {
    __shared__ float red[16];
    const int tid = threadIdx.x;
    float s = 0.f;
    for (int i = tid; i < NX; i += 1024) {
        float cmax = u2f_ord(rowmax_u[i]) * inv_nx[i];
        float x = 1.0f - cmax;
        s += x * x;
    }
    #pragma unroll
    for (int off = 32; off; off >>= 1) s += __shfl_xor(s, off);
    if ((tid & 63) == 0) red[tid >> 6] = s;
    __syncthreads();
    if (tid < 16) {
        float t = red[tid];
        t += __shfl_xor(t, 8);
        t += __shfl_xor(t, 4);
        t += __shfl_xor(t, 2);
        t += __shfl_xor(t, 1);
        if (tid == 0) {
            const float log_const = logf(2.0f) - logf(0.3f) - 0.5f * logf(2.0f * (float)M_PI);
            out[0] = (float)NX * log_const - t * (1.0f / (2.0f * 0.3f * 0.3f));
        }
    }
}

extern "C" void kernel_launch(void* const* d_in, const int* in_sizes, int n_in,
                              void* d_out, int out_size, void* d_ws, size_t ws_size,
                              hipStream_t stream) {
    const float* ex = (const float*)d_in[0];
    const float* ey = (const float*)d_in[1];
    float* inv_nx        = (float*)d_ws;
    float* inv_ny        = inv_nx + NX;
    unsigned int* rowmax = (unsigned int*)(inv_ny + NY);
    float* out           = (float*)d_out;

    const size_t head = (size_t)(NX + NY + NX) * 4;          // norms + rowmax
    const size_t need = head + (size_t)(NX + NY) * KD;       // + i8 copies

    if (ws_size >= need) {
        char* exq = (char*)d_ws + head;
        char* eyq = exq + (size_t)NX * KD;
        convert_kernel<<<dim3((NX + NY) / 4), 256, 0, stream>>>(
            ex, ey, exq, eyq, inv_nx, inv_ny, rowmax);
        gemm_i8_kernel<<<dim3(NX / BM, NY / BN), 512, 0, stream>>>(
            exq, eyq, inv_ny, rowmax);
    } else {
        prep_kernel<<<dim3(NX / 4, 2), 256, 0, stream>>>(ex, ey, inv_nx, inv_ny, rowmax);
        gemmmax_f32_kernel<<<dim3(NX / 128, NY / 128), 256, 0, stream>>>(
            ex, ey, inv_ny, rowmax);
    }
    finalize_kernel<<<1, 1024, 0, stream>>>(rowmax, inv_nx, out);
}